// Round 6
// baseline (312.795 us; speedup 1.0000x reference)
//
#include <hip/hip_runtime.h>
#include <hip/hip_bf16.h>

constexpr int Bn = 64;
constexpr int Ln = 2048;
constexpr int Dn = 128;
constexpr int Hn = 4;
constexpr int An = 128;
constexpr int Mn = 16;
constexpr int Vn = 100000;
constexpr int HDn = 32;
constexpr float GAMMA = 0.3f;
constexpr float BETA = 1.0f;

constexpr int PHIP_BLOCKS = 1024;   // k_phip grid; also k_red's reduction depth

// workspace layout (in floats); all offsets are multiples of 4 -> 16B aligned
constexpr size_t OFF_PHIP  = 0;                     // 16*128   = 2048
constexpr size_t OFF_SIZEP = 2048;                  // 16
constexpr size_t OFF_PHIQ  = 2064;                  // 64*128   = 8192
constexpr size_t OFF_SUMPS = 10256;                 // 64*16    = 1024
constexpr size_t OFF_C     = 11280;                 // 64*4*128 = 32768
constexpr size_t OFF_PT    = 44048;                 // V*16     = 1600000
constexpr size_t OFF_PART  = OFF_PT + (size_t)Vn * 16;          // 1644048
constexpr size_t WS_FLOATS_PT   = OFF_PART;                      // pT tier
constexpr size_t WS_FLOATS_PART = OFF_PART + (size_t)PHIP_BLOCKS * Mn * An;  // partials tier

// native vector type for nontemporal builtins (HIP float4 is a class type)
typedef float nfloat4 __attribute__((ext_vector_type(4)));

__device__ __forceinline__ float sigm(float x) { return 1.f / (1.f + __expf(-x)); }

// ---------------------------------------------------------------------------
// K0: pT[v,m] = sigmoid(phi[m,v]); sizeP[m] = sum_v.  grid ceil(V/256) x 256.
// ---------------------------------------------------------------------------
__global__ __launch_bounds__(256) void k_pt(const float* __restrict__ phi,
                                            float* __restrict__ pT,
                                            float* __restrict__ sizeP) {
    __shared__ float szl[Mn];
    const int t = threadIdx.x;
    if (t < Mn) szl[t] = 0.f;
    __syncthreads();
    const int v = (int)blockIdx.x * 256 + t;
    if (v < Vn) {
        float p[Mn];
#pragma unroll
        for (int m = 0; m < Mn; ++m) p[m] = sigm(phi[(size_t)m * Vn + v]);
        float4* dst = (float4*)&pT[(size_t)v * 16];
        dst[0] = make_float4(p[0], p[1], p[2], p[3]);
        dst[1] = make_float4(p[4], p[5], p[6], p[7]);
        dst[2] = make_float4(p[8], p[9], p[10], p[11]);
        dst[3] = make_float4(p[12], p[13], p[14], p[15]);
#pragma unroll
        for (int m = 0; m < Mn; ++m) atomicAdd(&szl[m], p[m]);
    }
    __syncthreads();
    if (t < Mn) atomicAdd(&sizeP[t], szl[t]);
}

// ---------------------------------------------------------------------------
// K1: PhiP[m,a] = sum_v pT[v,m] * E[v,a].
// v2 change: E stream prefetch deepened to 2 iterations (HBM latency ~900cyc
// >> per-iter compute ~170cyc; 1-deep left ~750cyc exposed). pT stays 1-deep
// (6.4MB, L2-resident broadcast). +4 VGPR.
// ---------------------------------------------------------------------------
__global__ __launch_bounds__(256, 4) void k_phip(const float* __restrict__ E,
                                                 const float* __restrict__ pT,
                                                 float* __restrict__ PhiP,
                                                 float* __restrict__ part,
                                                 int mode) {
    const int t = threadIdx.x;
    const int wv = t >> 6, lane = t & 63;
    const int c = lane & 31;      // float4 column of E row
    const int rh = lane >> 5;     // row within pair
    const int W = (int)gridDim.x * 4;
    const int w = (int)blockIdx.x * 4 + wv;
    constexpr int NP = Vn / 2;    // 50000 row-pairs

    const float4* E4 = (const float4*)E;
    const float4* P4 = (const float4*)pT;

    float4 acc[Mn];
#pragma unroll
    for (int m = 0; m < Mn; ++m) acc[m] = make_float4(0.f, 0.f, 0.f, 0.f);

    int i = w;
    float4 e_n  = make_float4(0.f, 0.f, 0.f, 0.f);
    float4 e_n2 = e_n;
    float4 pf_n0 = e_n, pf_n1 = e_n, pf_n2 = e_n, pf_n3 = e_n;
    if (i < NP) {
        const size_t vr = (size_t)(2 * i + rh);
        e_n = E4[vr * 32 + c];
        pf_n0 = P4[vr * 4 + 0]; pf_n1 = P4[vr * 4 + 1];
        pf_n2 = P4[vr * 4 + 2]; pf_n3 = P4[vr * 4 + 3];
    }
    if (i + W < NP) {
        e_n2 = E4[(size_t)(2 * (i + W) + rh) * 32 + c];
    }
    while (i < NP) {
        const float4 e = e_n;
        const float4 f0 = pf_n0, f1 = pf_n1, f2 = pf_n2, f3 = pf_n3;
        const int in  = i + W;
        const int in2 = in + W;
        e_n = e_n2;
        if (in2 < NP) {        // E prefetch 2 ahead
            e_n2 = E4[(size_t)(2 * in2 + rh) * 32 + c];
        }
        if (in < NP) {         // pT prefetch 1 ahead (L2-hit)
            const size_t vr = (size_t)(2 * in + rh);
            pf_n0 = P4[vr * 4 + 0]; pf_n1 = P4[vr * 4 + 1];
            pf_n2 = P4[vr * 4 + 2]; pf_n3 = P4[vr * 4 + 3];
        }
        float pm[Mn];
        pm[0] = f0.x; pm[1] = f0.y; pm[2] = f0.z; pm[3] = f0.w;
        pm[4] = f1.x; pm[5] = f1.y; pm[6] = f1.z; pm[7] = f1.w;
        pm[8] = f2.x; pm[9] = f2.y; pm[10] = f2.z; pm[11] = f2.w;
        pm[12] = f3.x; pm[13] = f3.y; pm[14] = f3.z; pm[15] = f3.w;
#pragma unroll
        for (int m = 0; m < Mn; ++m) {
            acc[m].x += pm[m] * e.x; acc[m].y += pm[m] * e.y;
            acc[m].z += pm[m] * e.z; acc[m].w += pm[m] * e.w;
        }
        i = in;
    }

    // reduce row-halves: lanes l and l^32 share column c
#pragma unroll
    for (int m = 0; m < Mn; ++m) {
        acc[m].x += __shfl_xor(acc[m].x, 32);
        acc[m].y += __shfl_xor(acc[m].y, 32);
        acc[m].z += __shfl_xor(acc[m].z, 32);
        acc[m].w += __shfl_xor(acc[m].w, 32);
    }
    __shared__ float4 red[4 * Mn * 32];   // 32 KB, used only after the loop
    if (lane < 32) {
#pragma unroll
        for (int m = 0; m < Mn; ++m) red[(wv * Mn + m) * 32 + c] = acc[m];
    }
    __syncthreads();
#pragma unroll
    for (int r = 0; r < 2; ++r) {
        const int idx = t + r * 256;          // 0..511 -> (m = idx>>5, a = idx&31)
        const int m = idx >> 5, a = idx & 31;
        const float4 s0 = red[(0 * Mn + m) * 32 + a];
        const float4 s1 = red[(1 * Mn + m) * 32 + a];
        const float4 s2 = red[(2 * Mn + m) * 32 + a];
        const float4 s3 = red[(3 * Mn + m) * 32 + a];
        const float4 s = make_float4(s0.x + s1.x + s2.x + s3.x,
                                     s0.y + s1.y + s2.y + s3.y,
                                     s0.z + s1.z + s2.z + s3.z,
                                     s0.w + s1.w + s2.w + s3.w);
        if (mode == 0) {
            ((float4*)part)[(size_t)blockIdx.x * 512 + idx] = s;   // coalesced
        } else {
            float* dst = &PhiP[(size_t)m * An + a * 4];
            atomicAdd(dst + 0, s.x); atomicAdd(dst + 1, s.y);
            atomicAdd(dst + 2, s.z); atomicAdd(dst + 3, s.w);
        }
    }
}

// ---------------------------------------------------------------------------
// K1c: PhiP[m*128+a] = sum_k part[k][m*128+a].  grid (Mn, 64) x 128.
// KCH=16 per block: 64 deterministic per-chunk sums, 64 atomics per address.
// NOTE: grid.y MUST be PHIP_BLOCKS/KCH = 64 (round-4 failure was grid.y=8).
// ---------------------------------------------------------------------------
__global__ __launch_bounds__(128) void k_red(const float* __restrict__ part,
                                             float* __restrict__ PhiP) {
    const int m = blockIdx.x;
    const int kc = blockIdx.y;
    const int a = threadIdx.x;
    constexpr int KCH = PHIP_BLOCKS / 64;   // 16
    float s = 0.f;
    const float* src = part + (size_t)kc * KCH * (Mn * An) + (size_t)m * An + a;
#pragma unroll
    for (int k = 0; k < KCH; ++k) s += src[(size_t)k * (Mn * An)];
    atomicAdd(&PhiP[(size_t)m * An + a], s);
}

// ---------------------------------------------------------------------------
// K1-fallback (small ws): round-2 structure, reads phi directly, owns sizeP.
// ---------------------------------------------------------------------------
__global__ __launch_bounds__(256) void k_phip_fb(const float* __restrict__ phi,
                                                 const float* __restrict__ E,
                                                 float* __restrict__ PhiP,
                                                 float* __restrict__ sizeP) {
    __shared__ float pv[64 * 16];
    __shared__ float szl[Mn];
    const int t = threadIdx.x;
    const int a4 = t & 31;
    const int g = t >> 5;
    const int vloc = t >> 2;
    const int mbase = 4 * (t & 3);

    if (t < Mn) szl[t] = 0.f;

    float4 acc0 = make_float4(0.f, 0.f, 0.f, 0.f);
    float4 acc1 = make_float4(0.f, 0.f, 0.f, 0.f);
    float4 szacc = make_float4(0.f, 0.f, 0.f, 0.f);

    for (int v0 = blockIdx.x * 64; v0 < Vn; v0 += gridDim.x * 64) {
        __syncthreads();
        const int v = v0 + vloc;
        float4 pj = make_float4(0.f, 0.f, 0.f, 0.f);
        if (v < Vn) {
            pj.x = sigm(phi[(size_t)(mbase + 0) * Vn + v]);
            pj.y = sigm(phi[(size_t)(mbase + 1) * Vn + v]);
            pj.z = sigm(phi[(size_t)(mbase + 2) * Vn + v]);
            pj.w = sigm(phi[(size_t)(mbase + 3) * Vn + v]);
        }
        *(float4*)&pv[4 * t] = pj;
        szacc.x += pj.x; szacc.y += pj.y; szacc.z += pj.z; szacc.w += pj.w;
        __syncthreads();
        const int vmax = min(64, Vn - v0);
#pragma unroll 8
        for (int vv = 0; vv < vmax; ++vv) {
            const float4 e = *(const float4*)&E[(size_t)(v0 + vv) * An + a4 * 4];
            const float2 pm = *(const float2*)&pv[vv * 16 + g * 2];
            acc0.x += pm.x * e.x; acc0.y += pm.x * e.y; acc0.z += pm.x * e.z; acc0.w += pm.x * e.w;
            acc1.x += pm.y * e.x; acc1.y += pm.y * e.y; acc1.z += pm.y * e.z; acc1.w += pm.y * e.w;
        }
    }
    {
        float* d0 = &PhiP[(size_t)(2 * g + 0) * An + a4 * 4];
        float* d1 = &PhiP[(size_t)(2 * g + 1) * An + a4 * 4];
        atomicAdd(d0 + 0, acc0.x); atomicAdd(d0 + 1, acc0.y);
        atomicAdd(d0 + 2, acc0.z); atomicAdd(d0 + 3, acc0.w);
        atomicAdd(d1 + 0, acc1.x); atomicAdd(d1 + 1, acc1.y);
        atomicAdd(d1 + 2, acc1.z); atomicAdd(d1 + 3, acc1.w);
    }
    atomicAdd(&szl[mbase + 0], szacc.x);
    atomicAdd(&szl[mbase + 1], szacc.y);
    atomicAdd(&szl[mbase + 2], szacc.z);
    atomicAdd(&szl[mbase + 3], szacc.w);
    __syncthreads();
    if (t < Mn) atomicAdd(&sizeP[t], szl[t]);
}

// ---------------------------------------------------------------------------
// K2: PhiQ[b,a] = sum_{i in seg b} E[qid[i],a];  sumpS[b,m] = sum_i pT[qid[i],m]
// grid (64 splits, B). block 256.
// v2 change: E-gather widened to 8 rows in flight per thread (one full round
// covers the 64-atom chunk; old code ran 2 serial 4-deep rounds).
// ---------------------------------------------------------------------------
__global__ __launch_bounds__(256) void k_phiq(const int* __restrict__ qid,
                                              const int* __restrict__ offs,
                                              const float* __restrict__ E,
                                              const float* __restrict__ phi,
                                              const float* __restrict__ pT,
                                              int usepT,
                                              float* __restrict__ PhiQ,
                                              float* __restrict__ sumpS) {
    const int b = blockIdx.y;
    const int s0 = offs[b], s1 = offs[b + 1];
    const int len = s1 - s0;
    const int nsplit = (int)gridDim.x;
    const int chunk = (len + nsplit - 1) / nsplit;
    const int start = s0 + (int)blockIdx.x * chunk;
    const int end = min(start + chunk, s1);
    const int t = threadIdx.x;

    __shared__ float phl[8 * 128];
    __shared__ float sP[Mn];
    if (t < Mn) sP[t] = 0.f;

    {
        const int a4 = t & 31, sub = t >> 5;
        float4 acc = make_float4(0.f, 0.f, 0.f, 0.f);
        const float4* E4 = (const float4*)E;
        int i = start + sub;
        for (; i + 56 < end; i += 64) {
            int q[8];
#pragma unroll
            for (int k = 0; k < 8; ++k) q[k] = qid[i + 8 * k];
            float4 e[8];
#pragma unroll
            for (int k = 0; k < 8; ++k) e[k] = E4[(size_t)q[k] * 32 + a4];
#pragma unroll
            for (int k = 0; k < 8; ++k) {
                acc.x += e[k].x; acc.y += e[k].y;
                acc.z += e[k].z; acc.w += e[k].w;
            }
        }
        for (; i < end; i += 8) {
            const float4 e = E4[(size_t)qid[i] * 32 + a4];
            acc.x += e.x; acc.y += e.y; acc.z += e.z; acc.w += e.w;
        }
        *(float4*)&phl[sub * 128 + a4 * 4] = acc;
    }
    __syncthreads();
    if (t < 128) {
        float s = 0.f;
#pragma unroll
        for (int k = 0; k < 8; ++k) s += phl[k * 128 + t];
        atomicAdd(&PhiQ[(size_t)b * An + t], s);
    }

    float4 acc = make_float4(0.f, 0.f, 0.f, 0.f);
    const int m4 = t & 3, io = t >> 2;
    if (usepT) {
        const float4* pT4 = (const float4*)pT;
        int i = start + io;
        for (; i + 192 < end; i += 256) {
            const int q0 = qid[i], q1 = qid[i + 64], q2 = qid[i + 128], q3 = qid[i + 192];
            const float4 p0 = pT4[(size_t)q0 * 4 + m4];
            const float4 p1 = pT4[(size_t)q1 * 4 + m4];
            const float4 p2 = pT4[(size_t)q2 * 4 + m4];
            const float4 p3 = pT4[(size_t)q3 * 4 + m4];
            acc.x += p0.x + p1.x + p2.x + p3.x;
            acc.y += p0.y + p1.y + p2.y + p3.y;
            acc.z += p0.z + p1.z + p2.z + p3.z;
            acc.w += p0.w + p1.w + p2.w + p3.w;
        }
        for (; i < end; i += 64) {
            const float4 p = pT4[(size_t)qid[i] * 4 + m4];
            acc.x += p.x; acc.y += p.y; acc.z += p.z; acc.w += p.w;
        }
    } else {
        for (int i = start + io; i < end; i += 64) {
            const int q = qid[i];
            acc.x += sigm(phi[(size_t)(m4 * 4 + 0) * Vn + q]);
            acc.y += sigm(phi[(size_t)(m4 * 4 + 1) * Vn + q]);
            acc.z += sigm(phi[(size_t)(m4 * 4 + 2) * Vn + q]);
            acc.w += sigm(phi[(size_t)(m4 * 4 + 3) * Vn + q]);
        }
    }
#pragma unroll
    for (int off = 32; off >= 4; off >>= 1) {
        acc.x += __shfl_xor(acc.x, off);
        acc.y += __shfl_xor(acc.y, off);
        acc.z += __shfl_xor(acc.z, off);
        acc.w += __shfl_xor(acc.w, off);
    }
    if ((t & 63) < 4) {
        atomicAdd(&sP[m4 * 4 + 0], acc.x);
        atomicAdd(&sP[m4 * 4 + 1], acc.y);
        atomicAdd(&sP[m4 * 4 + 2], acc.z);
        atomicAdd(&sP[m4 * 4 + 3], acc.w);
    }
    __syncthreads();
    if (t < Mn) atomicAdd(&sumpS[(size_t)b * Mn + t], sP[t]);
}

// ---------------------------------------------------------------------------
// K3: per-b block (128 thr): BP, Vp, AQ, scores, softmax, Z, C[b,h,:]
// ---------------------------------------------------------------------------
__global__ __launch_bounds__(128) void k_small(const float* __restrict__ PhiP,
                                               const float* __restrict__ sizeP,
                                               const float* __restrict__ PhiQ,
                                               const float* __restrict__ sumpS,
                                               const int* __restrict__ offs,
                                               const float* __restrict__ W_A,
                                               const float* __restrict__ W_B,
                                               const float* __restrict__ W_val,
                                               const float* __restrict__ b_val,
                                               const float* __restrict__ W_out,
                                               const float* __restrict__ size_w,
                                               float* __restrict__ Cws) {
    const int b = blockIdx.x;
    const int i = threadIdx.x;
    __shared__ float BP[Mn * An];
    __shared__ float Vp[Mn * HDn];
    __shared__ float AQs[An];
    __shared__ float sc[Mn];
    __shared__ float attn[Mn];
    __shared__ float Zs[HDn];

    {
        const float4* wa = (const float4*)(W_A + (size_t)i * An);
        const float4* pq = (const float4*)(PhiQ + (size_t)b * An);
        float aq = 0.f;
        for (int q = 0; q < An / 4; ++q) {
            const float4 w = wa[q], p = pq[q];
            aq += w.x * p.x + w.y * p.y + w.z * p.z + w.w * p.w;
        }
        AQs[i] = aq;
    }
    {
        const float4* wb = (const float4*)(W_B + (size_t)i * An);
        for (int m = 0; m < Mn; ++m) {
            const float4* pp = (const float4*)(PhiP + (size_t)m * An);
            float s = 0.f;
            for (int q = 0; q < An / 4; ++q) {
                const float4 w = wb[q], p = pp[q];
                s += w.x * p.x + w.y * p.y + w.z * p.z + w.w * p.w;
            }
            BP[m * An + i] = s;
        }
    }
    if (i < HDn) {
        const float4* wv = (const float4*)(W_val + (size_t)i * An);
        for (int m = 0; m < Mn; ++m) {
            const float4* pp = (const float4*)(PhiP + (size_t)m * An);
            float s = 0.f;
            for (int q = 0; q < An / 4; ++q) {
                const float4 w = wv[q], p = pp[q];
                s += w.x * p.x + w.y * p.y + w.z * p.z + w.w * p.w;
            }
            Vp[m * HDn + i] = s + b_val[i];
        }
    }
    __syncthreads();

    const float szQ = (float)(offs[b + 1] - offs[b]);
    if (i < Mn) {
        float d = 0.f;
        for (int a = 0; a < An; ++a) d += AQs[a] * BP[i * An + a];
        const float delta = szQ + sizeP[i] - 2.f * sumpS[(size_t)b * Mn + i];
        sc[i] = -GAMMA * delta + BETA * d + size_w[0] * szQ + size_w[1] * sizeP[i];
    }
    __syncthreads();
    if (i < Mn) {
        float mx = sc[0];
        for (int m = 1; m < Mn; ++m) mx = fmaxf(mx, sc[m]);
        float sum = 0.f;
        for (int m = 0; m < Mn; ++m) sum += __expf(sc[m] - mx);
        attn[i] = __expf(sc[i] - mx) / sum;
    }
    __syncthreads();
    if (i < HDn) {
        float z = 0.f;
        for (int m = 0; m < Mn; ++m) z += attn[m] * Vp[m * HDn + i];
        Zs[i] = z;
    }
    __syncthreads();
    {
        const float* wo = W_out + (size_t)i * Dn;
#pragma unroll
        for (int h = 0; h < Hn; ++h) {
            float c = 0.f;
#pragma unroll
            for (int j = 0; j < HDn; ++j) c += Zs[j] * wo[h * HDn + j];
            Cws[((size_t)b * Hn + h) * Dn + i] = c;
        }
    }
}

// ---------------------------------------------------------------------------
// K4: out[b,l,:] = b_out + sum_h softmax_h(ts[b,l,:].W_gate[h]+b_gate) * C[b,h,:]
// v4: v2 structure (1 coalesced float4 load/lane, shuffle reduce — v3's DS
// reduction was a measured null) + 2-DEEP register prefetch: per-iter compute
// ~150cyc << HBM ~900cyc, so 1-deep left ~750cyc exposed per iter per wave.
// NT stores kept.
// ---------------------------------------------------------------------------
__global__ __launch_bounds__(256) void k_out(const float* __restrict__ ts,
                                             const float* __restrict__ W_gate,
                                             const float* __restrict__ b_gate,
                                             const float* __restrict__ b_out,
                                             const float* __restrict__ Cws,
                                             float* __restrict__ out) {
    constexpr int CHUNK = 64;
    constexpr int NIT = CHUNK / 8;   // 8 iterations, 8 tokens in flight/block
    const int b = blockIdx.y;
    const int t = threadIdx.x;
    __shared__ float4 WgS[Hn * 32];
    __shared__ float4 CS[Hn * 32];
    __shared__ float4 boS[32];
    __shared__ float bgS[Hn];
    if (t < 128) WgS[t] = ((const float4*)W_gate)[t];
    else CS[t - 128] = ((const float4*)(Cws + (size_t)b * Hn * Dn))[t - 128];
    if (t < 32) boS[t] = ((const float4*)b_out)[t];
    if (t >= 64 && t < 64 + Hn) bgS[t - 64] = b_gate[t - 64];
    __syncthreads();

    const int sl = t & 31;
    const int tg = t >> 5;
    const size_t rowbase = (size_t)b * Ln + (size_t)blockIdx.x * CHUNK;
    const float4* x4 = (const float4*)ts + rowbase * 32;
    nfloat4* o4 = (nfloat4*)out + rowbase * 32;

    const float4 w0 = WgS[0 * 32 + sl], w1 = WgS[1 * 32 + sl];
    const float4 w2 = WgS[2 * 32 + sl], w3 = WgS[3 * 32 + sl];
    const float4 c0 = CS[0 * 32 + sl], c1 = CS[1 * 32 + sl];
    const float4 c2 = CS[2 * 32 + sl], c3 = CS[3 * 32 + sl];
    const float4 bo = boS[sl];
    const float bg0 = bgS[0], bg1 = bgS[1], bg2 = bgS[2], bg3 = bgS[3];

    float4 xa = x4[(size_t)tg * 32 + sl];            // it = 0
    float4 xb = x4[(size_t)(8 + tg) * 32 + sl];      // it = 1
    for (int it = 0; it < NIT; ++it) {
        const float4 x = xa;
        xa = xb;
        if (it + 2 < NIT)                            // prefetch 2 ahead
            xb = x4[(size_t)((it + 2) * 8 + tg) * 32 + sl];
        float a0 = x.x * w0.x + x.y * w0.y + x.z * w0.z + x.w * w0.w;
        float a1 = x.x * w1.x + x.y * w1.y + x.z * w1.z + x.w * w1.w;
        float a2 = x.x * w2.x + x.y * w2.y + x.z * w2.z + x.w * w2.w;
        float a3 = x.x * w3.x + x.y * w3.y + x.z * w3.z + x.w * w3.w;
#pragma unroll
        for (int off = 16; off > 0; off >>= 1) {
            a0 += __shfl_xor(a0, off);
            a1 += __shfl_xor(a1, off);
            a2 += __shfl_xor(a2, off);
            a3 += __shfl_xor(a3, off);
        }
        a0 += bg0; a1 += bg1; a2 += bg2; a3 += bg3;
        const float mx = fmaxf(fmaxf(a0, a1), fmaxf(a2, a3));
        const float e0 = __expf(a0 - mx), e1 = __expf(a1 - mx);
        const float e2 = __expf(a2 - mx), e3 = __expf(a3 - mx);
        const float inv = 1.f / (e0 + e1 + e2 + e3);
        const float g0 = e0 * inv, g1 = e1 * inv, g2 = e2 * inv, g3 = e3 * inv;
        nfloat4 o;
        o.x = bo.x + g0 * c0.x + g1 * c1.x + g2 * c2.x + g3 * c3.x;
        o.y = bo.y + g0 * c0.y + g1 * c1.y + g2 * c2.y + g3 * c3.y;
        o.z = bo.z + g0 * c0.z + g1 * c1.z + g2 * c2.z + g3 * c3.z;
        o.w = bo.w + g0 * c0.w + g1 * c1.w + g2 * c2.w + g3 * c3.w;
        __builtin_nontemporal_store(o, &o4[(size_t)(it * 8 + tg) * 32 + sl]);
    }
}

extern "C" void kernel_launch(void* const* d_in, const int* in_sizes, int n_in,
                              void* d_out, int out_size, void* d_ws, size_t ws_size,
                              hipStream_t stream) {
    const float* ts     = (const float*)d_in[0];
    const int*   qid    = (const int*)d_in[1];
    const int*   offs   = (const int*)d_in[2];
    const float* E      = (const float*)d_in[3];
    const float* phi    = (const float*)d_in[4];
    const float* W_A    = (const float*)d_in[5];
    const float* W_B    = (const float*)d_in[6];
    const float* W_val  = (const float*)d_in[7];
    const float* b_val  = (const float*)d_in[8];
    const float* W_gate = (const float*)d_in[9];
    const float* b_gate = (const float*)d_in[10];
    const float* W_out  = (const float*)d_in[11];
    const float* b_out  = (const float*)d_in[12];
    const float* size_w = (const float*)d_in[13];
    float* out = (float*)d_out;
    float* ws  = (float*)d_ws;

    float* PhiP  = ws + OFF_PHIP;
    float* sizeP = ws + OFF_SIZEP;
    float* PhiQ  = ws + OFF_PHIQ;
    float* sumpS = ws + OFF_SUMPS;
    float* Cws   = ws + OFF_C;
    float* pT    = ws + OFF_PT;
    float* part  = ws + OFF_PART;
    const int usepT   = (ws_size >= WS_FLOATS_PT * sizeof(float)) ? 1 : 0;
    const int usePart = (ws_size >= WS_FLOATS_PART * sizeof(float)) ? 1 : 0;

    hipMemsetAsync(ws, 0, OFF_C * sizeof(float), stream);  // zero accumulators
    if (usepT) {
        k_pt<<<dim3((Vn + 255) / 256), dim3(256), 0, stream>>>(phi, pT, sizeP);
        k_phip<<<dim3(PHIP_BLOCKS), dim3(256), 0, stream>>>(E, pT, PhiP, part,
                                                            usePart ? 0 : 1);
        if (usePart)
            k_red<<<dim3(Mn, 64), dim3(128), 0, stream>>>(part, PhiP);
    } else {
        k_phip_fb<<<dim3(512), dim3(256), 0, stream>>>(phi, E, PhiP, sizeP);
    }
    k_phiq<<<dim3(64, Bn), dim3(256), 0, stream>>>(qid, offs, E, phi, pT, usepT, PhiQ, sumpS);
    k_small<<<dim3(Bn), dim3(128), 0, stream>>>(PhiP, sizeP, PhiQ, sumpS, offs,
                                                W_A, W_B, W_val, b_val, W_out, size_w, Cws);
    k_out<<<dim3(Ln / 64, Bn), dim3(256), 0, stream>>>(ts, W_gate, b_gate, b_out, Cws, out);
}

// Round 7
// 288.732 us; speedup vs baseline: 1.0833x; 1.0833x over previous
//
#include <hip/hip_runtime.h>
#include <hip/hip_bf16.h>

constexpr int Bn = 64;
constexpr int Ln = 2048;
constexpr int Dn = 128;
constexpr int Hn = 4;
constexpr int An = 128;
constexpr int Mn = 16;
constexpr int Vn = 100000;
constexpr int HDn = 32;
constexpr float GAMMA = 0.3f;
constexpr float BETA = 1.0f;

constexpr int PHIP_BLOCKS = 1024;   // k_phip grid; also k_red's reduction depth

// workspace layout (in floats); all offsets are multiples of 4 -> 16B aligned
constexpr size_t OFF_PHIP  = 0;                     // 16*128   = 2048
constexpr size_t OFF_SIZEP = 2048;                  // 16
constexpr size_t OFF_PHIQ  = 2064;                  // 64*128   = 8192
constexpr size_t OFF_SUMPS = 10256;                 // 64*16    = 1024
constexpr size_t OFF_C     = 11280;                 // 64*4*128 = 32768
constexpr size_t OFF_PT    = 44048;                 // V*16     = 1600000
constexpr size_t OFF_PART  = OFF_PT + (size_t)Vn * 16;          // 1644048
constexpr size_t WS_FLOATS_PT   = OFF_PART;                      // pT tier
constexpr size_t WS_FLOATS_PART = OFF_PART + (size_t)PHIP_BLOCKS * Mn * An;  // partials tier

// native vector type for nontemporal builtins (HIP float4 is a class type)
typedef float nfloat4 __attribute__((ext_vector_type(4)));

__device__ __forceinline__ float sigm(float x) { return 1.f / (1.f + __expf(-x)); }

// ---------------------------------------------------------------------------
// K0: pT[v,m] = sigmoid(phi[m,v]); sizeP[m] = sum_v.  grid ceil(V/256) x 256.
// v2: sizeP via 6-level shuffle butterfly + ONE LDS atomic per wave per m.
// (old: 16 per-thread LDS atomics, all 64 lanes same address with distinct
// values -> 64-deep HW serialization x16 m x4 waves = ~4096 serialized slots
// per block. This kernel is on the critical path of everything.)
// ---------------------------------------------------------------------------
__global__ __launch_bounds__(256) void k_pt(const float* __restrict__ phi,
                                            float* __restrict__ pT,
                                            float* __restrict__ sizeP) {
    __shared__ float szl[Mn];
    const int t = threadIdx.x;
    const int lane = t & 63;
    if (t < Mn) szl[t] = 0.f;
    __syncthreads();
    const int v = (int)blockIdx.x * 256 + t;
    float p[Mn];
#pragma unroll
    for (int m = 0; m < Mn; ++m)
        p[m] = (v < Vn) ? sigm(phi[(size_t)m * Vn + v]) : 0.f;
    if (v < Vn) {
        float4* dst = (float4*)&pT[(size_t)v * 16];
        dst[0] = make_float4(p[0], p[1], p[2], p[3]);
        dst[1] = make_float4(p[4], p[5], p[6], p[7]);
        dst[2] = make_float4(p[8], p[9], p[10], p[11]);
        dst[3] = make_float4(p[12], p[13], p[14], p[15]);
    }
#pragma unroll
    for (int m = 0; m < Mn; ++m) {
        float s = p[m];
        s += __shfl_xor(s, 32);
        s += __shfl_xor(s, 16);
        s += __shfl_xor(s, 8);
        s += __shfl_xor(s, 4);
        s += __shfl_xor(s, 2);
        s += __shfl_xor(s, 1);
        if (lane == 0) atomicAdd(&szl[m], s);
    }
    __syncthreads();
    if (t < Mn) atomicAdd(&sizeP[t], szl[t]);
}

// ---------------------------------------------------------------------------
// K1: PhiP[m,a] = sum_v pT[v,m] * E[v,a].
// E stream prefetch 2-deep; pT 1-deep (L2-resident broadcast).
// ---------------------------------------------------------------------------
__global__ __launch_bounds__(256, 4) void k_phip(const float* __restrict__ E,
                                                 const float* __restrict__ pT,
                                                 float* __restrict__ PhiP,
                                                 float* __restrict__ part,
                                                 int mode) {
    const int t = threadIdx.x;
    const int wv = t >> 6, lane = t & 63;
    const int c = lane & 31;      // float4 column of E row
    const int rh = lane >> 5;     // row within pair
    const int W = (int)gridDim.x * 4;
    const int w = (int)blockIdx.x * 4 + wv;
    constexpr int NP = Vn / 2;    // 50000 row-pairs

    const float4* E4 = (const float4*)E;
    const float4* P4 = (const float4*)pT;

    float4 acc[Mn];
#pragma unroll
    for (int m = 0; m < Mn; ++m) acc[m] = make_float4(0.f, 0.f, 0.f, 0.f);

    int i = w;
    float4 e_n  = make_float4(0.f, 0.f, 0.f, 0.f);
    float4 e_n2 = e_n;
    float4 pf_n0 = e_n, pf_n1 = e_n, pf_n2 = e_n, pf_n3 = e_n;
    if (i < NP) {
        const size_t vr = (size_t)(2 * i + rh);
        e_n = E4[vr * 32 + c];
        pf_n0 = P4[vr * 4 + 0]; pf_n1 = P4[vr * 4 + 1];
        pf_n2 = P4[vr * 4 + 2]; pf_n3 = P4[vr * 4 + 3];
    }
    if (i + W < NP) {
        e_n2 = E4[(size_t)(2 * (i + W) + rh) * 32 + c];
    }
    while (i < NP) {
        const float4 e = e_n;
        const float4 f0 = pf_n0, f1 = pf_n1, f2 = pf_n2, f3 = pf_n3;
        const int in  = i + W;
        const int in2 = in + W;
        e_n = e_n2;
        if (in2 < NP) {        // E prefetch 2 ahead
            e_n2 = E4[(size_t)(2 * in2 + rh) * 32 + c];
        }
        if (in < NP) {         // pT prefetch 1 ahead (L2-hit)
            const size_t vr = (size_t)(2 * in + rh);
            pf_n0 = P4[vr * 4 + 0]; pf_n1 = P4[vr * 4 + 1];
            pf_n2 = P4[vr * 4 + 2]; pf_n3 = P4[vr * 4 + 3];
        }
        float pm[Mn];
        pm[0] = f0.x; pm[1] = f0.y; pm[2] = f0.z; pm[3] = f0.w;
        pm[4] = f1.x; pm[5] = f1.y; pm[6] = f1.z; pm[7] = f1.w;
        pm[8] = f2.x; pm[9] = f2.y; pm[10] = f2.z; pm[11] = f2.w;
        pm[12] = f3.x; pm[13] = f3.y; pm[14] = f3.z; pm[15] = f3.w;
#pragma unroll
        for (int m = 0; m < Mn; ++m) {
            acc[m].x += pm[m] * e.x; acc[m].y += pm[m] * e.y;
            acc[m].z += pm[m] * e.z; acc[m].w += pm[m] * e.w;
        }
        i = in;
    }

    // reduce row-halves: lanes l and l^32 share column c
#pragma unroll
    for (int m = 0; m < Mn; ++m) {
        acc[m].x += __shfl_xor(acc[m].x, 32);
        acc[m].y += __shfl_xor(acc[m].y, 32);
        acc[m].z += __shfl_xor(acc[m].z, 32);
        acc[m].w += __shfl_xor(acc[m].w, 32);
    }
    __shared__ float4 red[4 * Mn * 32];   // 32 KB, used only after the loop
    if (lane < 32) {
#pragma unroll
        for (int m = 0; m < Mn; ++m) red[(wv * Mn + m) * 32 + c] = acc[m];
    }
    __syncthreads();
#pragma unroll
    for (int r = 0; r < 2; ++r) {
        const int idx = t + r * 256;          // 0..511 -> (m = idx>>5, a = idx&31)
        const int m = idx >> 5, a = idx & 31;
        const float4 s0 = red[(0 * Mn + m) * 32 + a];
        const float4 s1 = red[(1 * Mn + m) * 32 + a];
        const float4 s2 = red[(2 * Mn + m) * 32 + a];
        const float4 s3 = red[(3 * Mn + m) * 32 + a];
        const float4 s = make_float4(s0.x + s1.x + s2.x + s3.x,
                                     s0.y + s1.y + s2.y + s3.y,
                                     s0.z + s1.z + s2.z + s3.z,
                                     s0.w + s1.w + s2.w + s3.w);
        if (mode == 0) {
            ((float4*)part)[(size_t)blockIdx.x * 512 + idx] = s;   // coalesced
        } else {
            float* dst = &PhiP[(size_t)m * An + a * 4];
            atomicAdd(dst + 0, s.x); atomicAdd(dst + 1, s.y);
            atomicAdd(dst + 2, s.z); atomicAdd(dst + 3, s.w);
        }
    }
}

// ---------------------------------------------------------------------------
// K1c: PhiP[m*128+a] = sum_k part[k][m*128+a].  grid (Mn, 64) x 128.
// KCH=16 per block: 64 deterministic per-chunk sums, 64 atomics per address.
// NOTE: grid.y MUST be PHIP_BLOCKS/KCH = 64 (round-4 failure was grid.y=8).
// ---------------------------------------------------------------------------
__global__ __launch_bounds__(128) void k_red(const float* __restrict__ part,
                                             float* __restrict__ PhiP) {
    const int m = blockIdx.x;
    const int kc = blockIdx.y;
    const int a = threadIdx.x;
    constexpr int KCH = PHIP_BLOCKS / 64;   // 16
    float s = 0.f;
    const float* src = part + (size_t)kc * KCH * (Mn * An) + (size_t)m * An + a;
#pragma unroll
    for (int k = 0; k < KCH; ++k) s += src[(size_t)k * (Mn * An)];
    atomicAdd(&PhiP[(size_t)m * An + a], s);
}

// ---------------------------------------------------------------------------
// K1-fallback (small ws): round-2 structure, reads phi directly, owns sizeP.
// ---------------------------------------------------------------------------
__global__ __launch_bounds__(256) void k_phip_fb(const float* __restrict__ phi,
                                                 const float* __restrict__ E,
                                                 float* __restrict__ PhiP,
                                                 float* __restrict__ sizeP) {
    __shared__ float pv[64 * 16];
    __shared__ float szl[Mn];
    const int t = threadIdx.x;
    const int a4 = t & 31;
    const int g = t >> 5;
    const int vloc = t >> 2;
    const int mbase = 4 * (t & 3);

    if (t < Mn) szl[t] = 0.f;

    float4 acc0 = make_float4(0.f, 0.f, 0.f, 0.f);
    float4 acc1 = make_float4(0.f, 0.f, 0.f, 0.f);
    float4 szacc = make_float4(0.f, 0.f, 0.f, 0.f);

    for (int v0 = blockIdx.x * 64; v0 < Vn; v0 += gridDim.x * 64) {
        __syncthreads();
        const int v = v0 + vloc;
        float4 pj = make_float4(0.f, 0.f, 0.f, 0.f);
        if (v < Vn) {
            pj.x = sigm(phi[(size_t)(mbase + 0) * Vn + v]);
            pj.y = sigm(phi[(size_t)(mbase + 1) * Vn + v]);
            pj.z = sigm(phi[(size_t)(mbase + 2) * Vn + v]);
            pj.w = sigm(phi[(size_t)(mbase + 3) * Vn + v]);
        }
        *(float4*)&pv[4 * t] = pj;
        szacc.x += pj.x; szacc.y += pj.y; szacc.z += pj.z; szacc.w += pj.w;
        __syncthreads();
        const int vmax = min(64, Vn - v0);
#pragma unroll 8
        for (int vv = 0; vv < vmax; ++vv) {
            const float4 e = *(const float4*)&E[(size_t)(v0 + vv) * An + a4 * 4];
            const float2 pm = *(const float2*)&pv[vv * 16 + g * 2];
            acc0.x += pm.x * e.x; acc0.y += pm.x * e.y; acc0.z += pm.x * e.z; acc0.w += pm.x * e.w;
            acc1.x += pm.y * e.x; acc1.y += pm.y * e.y; acc1.z += pm.y * e.z; acc1.w += pm.y * e.w;
        }
    }
    {
        float* d0 = &PhiP[(size_t)(2 * g + 0) * An + a4 * 4];
        float* d1 = &PhiP[(size_t)(2 * g + 1) * An + a4 * 4];
        atomicAdd(d0 + 0, acc0.x); atomicAdd(d0 + 1, acc0.y);
        atomicAdd(d0 + 2, acc0.z); atomicAdd(d0 + 3, acc0.w);
        atomicAdd(d1 + 0, acc1.x); atomicAdd(d1 + 1, acc1.y);
        atomicAdd(d1 + 2, acc1.z); atomicAdd(d1 + 3, acc1.w);
    }
    atomicAdd(&szl[mbase + 0], szacc.x);
    atomicAdd(&szl[mbase + 1], szacc.y);
    atomicAdd(&szl[mbase + 2], szacc.z);
    atomicAdd(&szl[mbase + 3], szacc.w);
    __syncthreads();
    if (t < Mn) atomicAdd(&sizeP[t], szl[t]);
}

// ---------------------------------------------------------------------------
// K2: PhiQ[b,a] = sum_{i in seg b} E[qid[i],a];  sumpS[b,m] = sum_i pT[qid[i],m]
// grid (64 splits, B). block 256.
// ---------------------------------------------------------------------------
__global__ __launch_bounds__(256) void k_phiq(const int* __restrict__ qid,
                                              const int* __restrict__ offs,
                                              const float* __restrict__ E,
                                              const float* __restrict__ phi,
                                              const float* __restrict__ pT,
                                              int usepT,
                                              float* __restrict__ PhiQ,
                                              float* __restrict__ sumpS) {
    const int b = blockIdx.y;
    const int s0 = offs[b], s1 = offs[b + 1];
    const int len = s1 - s0;
    const int nsplit = (int)gridDim.x;
    const int chunk = (len + nsplit - 1) / nsplit;
    const int start = s0 + (int)blockIdx.x * chunk;
    const int end = min(start + chunk, s1);
    const int t = threadIdx.x;

    __shared__ float phl[8 * 128];
    __shared__ float sP[Mn];
    if (t < Mn) sP[t] = 0.f;

    {
        const int a4 = t & 31, sub = t >> 5;
        float4 acc = make_float4(0.f, 0.f, 0.f, 0.f);
        const float4* E4 = (const float4*)E;
        int i = start + sub;
        for (; i + 56 < end; i += 64) {
            int q[8];
#pragma unroll
            for (int k = 0; k < 8; ++k) q[k] = qid[i + 8 * k];
            float4 e[8];
#pragma unroll
            for (int k = 0; k < 8; ++k) e[k] = E4[(size_t)q[k] * 32 + a4];
#pragma unroll
            for (int k = 0; k < 8; ++k) {
                acc.x += e[k].x; acc.y += e[k].y;
                acc.z += e[k].z; acc.w += e[k].w;
            }
        }
        for (; i < end; i += 8) {
            const float4 e = E4[(size_t)qid[i] * 32 + a4];
            acc.x += e.x; acc.y += e.y; acc.z += e.z; acc.w += e.w;
        }
        *(float4*)&phl[sub * 128 + a4 * 4] = acc;
    }
    __syncthreads();
    if (t < 128) {
        float s = 0.f;
#pragma unroll
        for (int k = 0; k < 8; ++k) s += phl[k * 128 + t];
        atomicAdd(&PhiQ[(size_t)b * An + t], s);
    }

    float4 acc = make_float4(0.f, 0.f, 0.f, 0.f);
    const int m4 = t & 3, io = t >> 2;
    if (usepT) {
        const float4* pT4 = (const float4*)pT;
        int i = start + io;
        for (; i + 192 < end; i += 256) {
            const int q0 = qid[i], q1 = qid[i + 64], q2 = qid[i + 128], q3 = qid[i + 192];
            const float4 p0 = pT4[(size_t)q0 * 4 + m4];
            const float4 p1 = pT4[(size_t)q1 * 4 + m4];
            const float4 p2 = pT4[(size_t)q2 * 4 + m4];
            const float4 p3 = pT4[(size_t)q3 * 4 + m4];
            acc.x += p0.x + p1.x + p2.x + p3.x;
            acc.y += p0.y + p1.y + p2.y + p3.y;
            acc.z += p0.z + p1.z + p2.z + p3.z;
            acc.w += p0.w + p1.w + p2.w + p3.w;
        }
        for (; i < end; i += 64) {
            const float4 p = pT4[(size_t)qid[i] * 4 + m4];
            acc.x += p.x; acc.y += p.y; acc.z += p.z; acc.w += p.w;
        }
    } else {
        for (int i = start + io; i < end; i += 64) {
            const int q = qid[i];
            acc.x += sigm(phi[(size_t)(m4 * 4 + 0) * Vn + q]);
            acc.y += sigm(phi[(size_t)(m4 * 4 + 1) * Vn + q]);
            acc.z += sigm(phi[(size_t)(m4 * 4 + 2) * Vn + q]);
            acc.w += sigm(phi[(size_t)(m4 * 4 + 3) * Vn + q]);
        }
    }
#pragma unroll
    for (int off = 32; off >= 4; off >>= 1) {
        acc.x += __shfl_xor(acc.x, off);
        acc.y += __shfl_xor(acc.y, off);
        acc.z += __shfl_xor(acc.z, off);
        acc.w += __shfl_xor(acc.w, off);
    }
    if ((t & 63) < 4) {
        atomicAdd(&sP[m4 * 4 + 0], acc.x);
        atomicAdd(&sP[m4 * 4 + 1], acc.y);
        atomicAdd(&sP[m4 * 4 + 2], acc.z);
        atomicAdd(&sP[m4 * 4 + 3], acc.w);
    }
    __syncthreads();
    if (t < Mn) atomicAdd(&sumpS[(size_t)b * Mn + t], sP[t]);
}

// ---------------------------------------------------------------------------
// K3: per-b block (128 thr): BP, Vp, AQ, scores, softmax, Z, C[b,h,:]
// ---------------------------------------------------------------------------
__global__ __launch_bounds__(128) void k_small(const float* __restrict__ PhiP,
                                               const float* __restrict__ sizeP,
                                               const float* __restrict__ PhiQ,
                                               const float* __restrict__ sumpS,
                                               const int* __restrict__ offs,
                                               const float* __restrict__ W_A,
                                               const float* __restrict__ W_B,
                                               const float* __restrict__ W_val,
                                               const float* __restrict__ b_val,
                                               const float* __restrict__ W_out,
                                               const float* __restrict__ size_w,
                                               float* __restrict__ Cws) {
    const int b = blockIdx.x;
    const int i = threadIdx.x;
    __shared__ float BP[Mn * An];
    __shared__ float Vp[Mn * HDn];
    __shared__ float AQs[An];
    __shared__ float sc[Mn];
    __shared__ float attn[Mn];
    __shared__ float Zs[HDn];

    {
        const float4* wa = (const float4*)(W_A + (size_t)i * An);
        const float4* pq = (const float4*)(PhiQ + (size_t)b * An);
        float aq = 0.f;
        for (int q = 0; q < An / 4; ++q) {
            const float4 w = wa[q], p = pq[q];
            aq += w.x * p.x + w.y * p.y + w.z * p.z + w.w * p.w;
        }
        AQs[i] = aq;
    }
    {
        const float4* wb = (const float4*)(W_B + (size_t)i * An);
        for (int m = 0; m < Mn; ++m) {
            const float4* pp = (const float4*)(PhiP + (size_t)m * An);
            float s = 0.f;
            for (int q = 0; q < An / 4; ++q) {
                const float4 w = wb[q], p = pp[q];
                s += w.x * p.x + w.y * p.y + w.z * p.z + w.w * p.w;
            }
            BP[m * An + i] = s;
        }
    }
    if (i < HDn) {
        const float4* wv = (const float4*)(W_val + (size_t)i * An);
        for (int m = 0; m < Mn; ++m) {
            const float4* pp = (const float4*)(PhiP + (size_t)m * An);
            float s = 0.f;
            for (int q = 0; q < An / 4; ++q) {
                const float4 w = wv[q], p = pp[q];
                s += w.x * p.x + w.y * p.y + w.z * p.z + w.w * p.w;
            }
            Vp[m * HDn + i] = s + b_val[i];
        }
    }
    __syncthreads();

    const float szQ = (float)(offs[b + 1] - offs[b]);
    if (i < Mn) {
        float d = 0.f;
        for (int a = 0; a < An; ++a) d += AQs[a] * BP[i * An + a];
        const float delta = szQ + sizeP[i] - 2.f * sumpS[(size_t)b * Mn + i];
        sc[i] = -GAMMA * delta + BETA * d + size_w[0] * szQ + size_w[1] * sizeP[i];
    }
    __syncthreads();
    if (i < Mn) {
        float mx = sc[0];
        for (int m = 1; m < Mn; ++m) mx = fmaxf(mx, sc[m]);
        float sum = 0.f;
        for (int m = 0; m < Mn; ++m) sum += __expf(sc[m] - mx);
        attn[i] = __expf(sc[i] - mx) / sum;
    }
    __syncthreads();
    if (i < HDn) {
        float z = 0.f;
        for (int m = 0; m < Mn; ++m) z += attn[m] * Vp[m * HDn + i];
        Zs[i] = z;
    }
    __syncthreads();
    {
        const float* wo = W_out + (size_t)i * Dn;
#pragma unroll
        for (int h = 0; h < Hn; ++h) {
            float c = 0.f;
#pragma unroll
            for (int j = 0; j < HDn; ++j) c += Zs[j] * wo[h * HDn + j];
            Cws[((size_t)b * Hn + h) * Dn + i] = c;
        }
    }
}

// ---------------------------------------------------------------------------
// K4: out[b,l,:] = b_out + sum_h softmax_h(ts[b,l,:].W_gate[h]+b_gate) * C[b,h,:]
// v5: BATCH-8 load phase. All 8 iteration loads issued back-to-back
// (independent, 8 outstanding VMEM per wave vs 2 before); compute consumes
// x[0] while 7 remain in flight (waitcnt vmcnt(N) semantics). This is the
// proper depth test of the memory-level-parallelism theory (depth-2 in r6
// was inadequate: needed ~latency/compute = 900/140 ~ 6-7).
// Fully unrolled -> static x[] indexing (no scratch). NT stores kept.
// ---------------------------------------------------------------------------
__global__ __launch_bounds__(256) void k_out(const float* __restrict__ ts,
                                             const float* __restrict__ W_gate,
                                             const float* __restrict__ b_gate,
                                             const float* __restrict__ b_out,
                                             const float* __restrict__ Cws,
                                             float* __restrict__ out) {
    constexpr int CHUNK = 64;
    constexpr int NIT = CHUNK / 8;   // 8 iterations, 8 tokens in flight/block
    const int b = blockIdx.y;
    const int t = threadIdx.x;
    __shared__ float4 WgS[Hn * 32];
    __shared__ float4 CS[Hn * 32];
    __shared__ float4 boS[32];
    __shared__ float bgS[Hn];
    if (t < 128) WgS[t] = ((const float4*)W_gate)[t];
    else CS[t - 128] = ((const float4*)(Cws + (size_t)b * Hn * Dn))[t - 128];
    if (t < 32) boS[t] = ((const float4*)b_out)[t];
    if (t >= 64 && t < 64 + Hn) bgS[t - 64] = b_gate[t - 64];
    __syncthreads();

    const int sl = t & 31;
    const int tg = t >> 5;
    const size_t rowbase = (size_t)b * Ln + (size_t)blockIdx.x * CHUNK;
    const float4* x4 = (const float4*)ts + rowbase * 32;
    nfloat4* o4 = (nfloat4*)out + rowbase * 32;

    const float4 w0 = WgS[0 * 32 + sl], w1 = WgS[1 * 32 + sl];
    const float4 w2 = WgS[2 * 32 + sl], w3 = WgS[3 * 32 + sl];
    const float4 c0 = CS[0 * 32 + sl], c1 = CS[1 * 32 + sl];
    const float4 c2 = CS[2 * 32 + sl], c3 = CS[3 * 32 + sl];
    const float4 bo = boS[sl];
    const float bg0 = bgS[0], bg1 = bgS[1], bg2 = bgS[2], bg3 = bgS[3];

    // batch-issue all 8 loads (independent; 8 outstanding per wave)
    float4 x[NIT];
#pragma unroll
    for (int k = 0; k < NIT; ++k)
        x[k] = x4[(size_t)(k * 8 + tg) * 32 + sl];

#pragma unroll
    for (int it = 0; it < NIT; ++it) {
        const float4 xi = x[it];
        float a0 = xi.x * w0.x + xi.y * w0.y + xi.z * w0.z + xi.w * w0.w;
        float a1 = xi.x * w1.x + xi.y * w1.y + xi.z * w1.z + xi.w * w1.w;
        float a2 = xi.x * w2.x + xi.y * w2.y + xi.z * w2.z + xi.w * w2.w;
        float a3 = xi.x * w3.x + xi.y * w3.y + xi.z * w3.z + xi.w * w3.w;
#pragma unroll
        for (int off = 16; off > 0; off >>= 1) {
            a0 += __shfl_xor(a0, off);
            a1 += __shfl_xor(a1, off);
            a2 += __shfl_xor(a2, off);
            a3 += __shfl_xor(a3, off);
        }
        a0 += bg0; a1 += bg1; a2 += bg2; a3 += bg3;
        const float mx = fmaxf(fmaxf(a0, a1), fmaxf(a2, a3));
        const float e0 = __expf(a0 - mx), e1 = __expf(a1 - mx);
        const float e2 = __expf(a2 - mx), e3 = __expf(a3 - mx);
        const float inv = 1.f / (e0 + e1 + e2 + e3);
        const float g0 = e0 * inv, g1 = e1 * inv, g2 = e2 * inv, g3 = e3 * inv;
        nfloat4 o;
        o.x = bo.x + g0 * c0.x + g1 * c1.x + g2 * c2.x + g3 * c3.x;
        o.y = bo.y + g0 * c0.y + g1 * c1.y + g2 * c2.y + g3 * c3.y;
        o.z = bo.z + g0 * c0.z + g1 * c1.z + g2 * c2.z + g3 * c3.z;
        o.w = bo.w + g0 * c0.w + g1 * c1.w + g2 * c2.w + g3 * c3.w;
        __builtin_nontemporal_store(o, &o4[(size_t)(it * 8 + tg) * 32 + sl]);
    }
}

extern "C" void kernel_launch(void* const* d_in, const int* in_sizes, int n_in,
                              void* d_out, int out_size, void* d_ws, size_t ws_size,
                              hipStream_t stream) {
    const float* ts     = (const float*)d_in[0];
    const int*   qid    = (const int*)d_in[1];
    const int*   offs   = (const int*)d_in[2];
    const float* E      = (const float*)d_in[3];
    const float* phi    = (const float*)d_in[4];
    const float* W_A    = (const float*)d_in[5];
    const float* W_B    = (const float*)d_in[6];
    const float* W_val  = (const float*)d_in[7];
    const float* b_val  = (const float*)d_in[8];
    const float* W_gate = (const float*)d_in[9];
    const float* b_gate = (const float*)d_in[10];
    const float* W_out  = (const float*)d_in[11];
    const float* b_out  = (const float*)d_in[12];
    const float* size_w = (const float*)d_in[13];
    float* out = (float*)d_out;
    float* ws  = (float*)d_ws;

    float* PhiP  = ws + OFF_PHIP;
    float* sizeP = ws + OFF_SIZEP;
    float* PhiQ  = ws + OFF_PHIQ;
    float* sumpS = ws + OFF_SUMPS;
    float* Cws   = ws + OFF_C;
    float* pT    = ws + OFF_PT;
    float* part  = ws + OFF_PART;
    const int usepT   = (ws_size >= WS_FLOATS_PT * sizeof(float)) ? 1 : 0;
    const int usePart = (ws_size >= WS_FLOATS_PART * sizeof(float)) ? 1 : 0;

    hipMemsetAsync(ws, 0, OFF_C * sizeof(float), stream);  // zero accumulators
    if (usepT) {
        k_pt<<<dim3((Vn + 255) / 256), dim3(256), 0, stream>>>(phi, pT, sizeP);
        k_phip<<<dim3(PHIP_BLOCKS), dim3(256), 0, stream>>>(E, pT, PhiP, part,
                                                            usePart ? 0 : 1);
        if (usePart)
            k_red<<<dim3(Mn, 64), dim3(128), 0, stream>>>(part, PhiP);
    } else {
        k_phip_fb<<<dim3(512), dim3(256), 0, stream>>>(phi, E, PhiP, sizeP);
    }
    k_phiq<<<dim3(64, Bn), dim3(256), 0, stream>>>(qid, offs, E, phi, pT, usepT, PhiQ, sumpS);
    k_small<<<dim3(Bn), dim3(128), 0, stream>>>(PhiP, sizeP, PhiQ, sumpS, offs,
                                                W_A, W_B, W_val, b_val, W_out, size_w, Cws);
    k_out<<<dim3(Ln / 64, Bn), dim3(256), 0, stream>>>(ts, W_gate, b_gate, b_out, Cws, out);
}

// Round 8
// 257.221 us; speedup vs baseline: 1.2161x; 1.1225x over previous
//
#include <hip/hip_runtime.h>
#include <hip/hip_bf16.h>

constexpr int Bn = 64;
constexpr int Ln = 2048;
constexpr int Dn = 128;
constexpr int Hn = 4;
constexpr int An = 128;
constexpr int Mn = 16;
constexpr int Vn = 100000;
constexpr int HDn = 32;
constexpr float GAMMA = 0.3f;
constexpr float BETA = 1.0f;

constexpr int PHIP_BLOCKS = 1024;   // k_phip grid; also k_red's reduction depth

// workspace layout (in floats); all offsets are multiples of 4 -> 16B aligned
constexpr size_t OFF_PHIP  = 0;                     // 16*128   = 2048
constexpr size_t OFF_SIZEP = 2048;                  // 16
constexpr size_t OFF_PHIQ  = 2064;                  // 64*128   = 8192
constexpr size_t OFF_SUMPS = 10256;                 // 64*16    = 1024
constexpr size_t OFF_C     = 11280;                 // 64*4*128 = 32768
constexpr size_t OFF_PT    = 44048;                 // V*16     = 1600000
constexpr size_t OFF_PART  = OFF_PT + (size_t)Vn * 16;          // 1644048
constexpr size_t WS_FLOATS_PT   = OFF_PART;                      // pT tier
constexpr size_t WS_FLOATS_PART = OFF_PART + (size_t)PHIP_BLOCKS * Mn * An;  // partials tier
// BP/Vp tier (b-independent precompute for k_small), placed after partials
constexpr size_t OFF_BP    = WS_FLOATS_PART;                     // 16*128 = 2048
constexpr size_t OFF_VP    = OFF_BP + (size_t)Mn * An;           // 16*32  = 512
constexpr size_t WS_FLOATS_BP = OFF_VP + (size_t)Mn * HDn;

// native vector type for nontemporal builtins (HIP float4 is a class type)
typedef float nfloat4 __attribute__((ext_vector_type(4)));

__device__ __forceinline__ float sigm(float x) { return 1.f / (1.f + __expf(-x)); }

// ---------------------------------------------------------------------------
// K0: pT[v,m] = sigmoid(phi[m,v]); sizeP[m] = sum_v.  grid ceil(V/256) x 256.
// v2: sizeP via 6-level shuffle butterfly + ONE LDS atomic per wave per m.
// (confirmed win: total -19us in r7)
// ---------------------------------------------------------------------------
__global__ __launch_bounds__(256) void k_pt(const float* __restrict__ phi,
                                            float* __restrict__ pT,
                                            float* __restrict__ sizeP) {
    __shared__ float szl[Mn];
    const int t = threadIdx.x;
    const int lane = t & 63;
    if (t < Mn) szl[t] = 0.f;
    __syncthreads();
    const int v = (int)blockIdx.x * 256 + t;
    float p[Mn];
#pragma unroll
    for (int m = 0; m < Mn; ++m)
        p[m] = (v < Vn) ? sigm(phi[(size_t)m * Vn + v]) : 0.f;
    if (v < Vn) {
        float4* dst = (float4*)&pT[(size_t)v * 16];
        dst[0] = make_float4(p[0], p[1], p[2], p[3]);
        dst[1] = make_float4(p[4], p[5], p[6], p[7]);
        dst[2] = make_float4(p[8], p[9], p[10], p[11]);
        dst[3] = make_float4(p[12], p[13], p[14], p[15]);
    }
#pragma unroll
    for (int m = 0; m < Mn; ++m) {
        float s = p[m];
        s += __shfl_xor(s, 32);
        s += __shfl_xor(s, 16);
        s += __shfl_xor(s, 8);
        s += __shfl_xor(s, 4);
        s += __shfl_xor(s, 2);
        s += __shfl_xor(s, 1);
        if (lane == 0) atomicAdd(&szl[m], s);
    }
    __syncthreads();
    if (t < Mn) atomicAdd(&sizeP[t], szl[t]);
}

// ---------------------------------------------------------------------------
// K1: PhiP[m,a] = sum_v pT[v,m] * E[v,a].
// ---------------------------------------------------------------------------
__global__ __launch_bounds__(256, 4) void k_phip(const float* __restrict__ E,
                                                 const float* __restrict__ pT,
                                                 float* __restrict__ PhiP,
                                                 float* __restrict__ part,
                                                 int mode) {
    const int t = threadIdx.x;
    const int wv = t >> 6, lane = t & 63;
    const int c = lane & 31;      // float4 column of E row
    const int rh = lane >> 5;     // row within pair
    const int W = (int)gridDim.x * 4;
    const int w = (int)blockIdx.x * 4 + wv;
    constexpr int NP = Vn / 2;    // 50000 row-pairs

    const float4* E4 = (const float4*)E;
    const float4* P4 = (const float4*)pT;

    float4 acc[Mn];
#pragma unroll
    for (int m = 0; m < Mn; ++m) acc[m] = make_float4(0.f, 0.f, 0.f, 0.f);

    int i = w;
    float4 e_n  = make_float4(0.f, 0.f, 0.f, 0.f);
    float4 e_n2 = e_n;
    float4 pf_n0 = e_n, pf_n1 = e_n, pf_n2 = e_n, pf_n3 = e_n;
    if (i < NP) {
        const size_t vr = (size_t)(2 * i + rh);
        e_n = E4[vr * 32 + c];
        pf_n0 = P4[vr * 4 + 0]; pf_n1 = P4[vr * 4 + 1];
        pf_n2 = P4[vr * 4 + 2]; pf_n3 = P4[vr * 4 + 3];
    }
    if (i + W < NP) {
        e_n2 = E4[(size_t)(2 * (i + W) + rh) * 32 + c];
    }
    while (i < NP) {
        const float4 e = e_n;
        const float4 f0 = pf_n0, f1 = pf_n1, f2 = pf_n2, f3 = pf_n3;
        const int in  = i + W;
        const int in2 = in + W;
        e_n = e_n2;
        if (in2 < NP) {        // E prefetch 2 ahead
            e_n2 = E4[(size_t)(2 * in2 + rh) * 32 + c];
        }
        if (in < NP) {         // pT prefetch 1 ahead (L2-hit)
            const size_t vr = (size_t)(2 * in + rh);
            pf_n0 = P4[vr * 4 + 0]; pf_n1 = P4[vr * 4 + 1];
            pf_n2 = P4[vr * 4 + 2]; pf_n3 = P4[vr * 4 + 3];
        }
        float pm[Mn];
        pm[0] = f0.x; pm[1] = f0.y; pm[2] = f0.z; pm[3] = f0.w;
        pm[4] = f1.x; pm[5] = f1.y; pm[6] = f1.z; pm[7] = f1.w;
        pm[8] = f2.x; pm[9] = f2.y; pm[10] = f2.z; pm[11] = f2.w;
        pm[12] = f3.x; pm[13] = f3.y; pm[14] = f3.z; pm[15] = f3.w;
#pragma unroll
        for (int m = 0; m < Mn; ++m) {
            acc[m].x += pm[m] * e.x; acc[m].y += pm[m] * e.y;
            acc[m].z += pm[m] * e.z; acc[m].w += pm[m] * e.w;
        }
        i = in;
    }

    // reduce row-halves: lanes l and l^32 share column c
#pragma unroll
    for (int m = 0; m < Mn; ++m) {
        acc[m].x += __shfl_xor(acc[m].x, 32);
        acc[m].y += __shfl_xor(acc[m].y, 32);
        acc[m].z += __shfl_xor(acc[m].z, 32);
        acc[m].w += __shfl_xor(acc[m].w, 32);
    }
    __shared__ float4 red[4 * Mn * 32];   // 32 KB, used only after the loop
    if (lane < 32) {
#pragma unroll
        for (int m = 0; m < Mn; ++m) red[(wv * Mn + m) * 32 + c] = acc[m];
    }
    __syncthreads();
#pragma unroll
    for (int r = 0; r < 2; ++r) {
        const int idx = t + r * 256;          // 0..511 -> (m = idx>>5, a = idx&31)
        const int m = idx >> 5, a = idx & 31;
        const float4 s0 = red[(0 * Mn + m) * 32 + a];
        const float4 s1 = red[(1 * Mn + m) * 32 + a];
        const float4 s2 = red[(2 * Mn + m) * 32 + a];
        const float4 s3 = red[(3 * Mn + m) * 32 + a];
        const float4 s = make_float4(s0.x + s1.x + s2.x + s3.x,
                                     s0.y + s1.y + s2.y + s3.y,
                                     s0.z + s1.z + s2.z + s3.z,
                                     s0.w + s1.w + s2.w + s3.w);
        if (mode == 0) {
            ((float4*)part)[(size_t)blockIdx.x * 512 + idx] = s;   // coalesced
        } else {
            float* dst = &PhiP[(size_t)m * An + a * 4];
            atomicAdd(dst + 0, s.x); atomicAdd(dst + 1, s.y);
            atomicAdd(dst + 2, s.z); atomicAdd(dst + 3, s.w);
        }
    }
}

// ---------------------------------------------------------------------------
// K1c: PhiP[m*128+a] = sum_k part[k][m*128+a].  grid (Mn, 64) x 128.
// NOTE: grid.y MUST be PHIP_BLOCKS/KCH = 64.
// ---------------------------------------------------------------------------
__global__ __launch_bounds__(128) void k_red(const float* __restrict__ part,
                                             float* __restrict__ PhiP) {
    const int m = blockIdx.x;
    const int kc = blockIdx.y;
    const int a = threadIdx.x;
    constexpr int KCH = PHIP_BLOCKS / 64;   // 16
    float s = 0.f;
    const float* src = part + (size_t)kc * KCH * (Mn * An) + (size_t)m * An + a;
#pragma unroll
    for (int k = 0; k < KCH; ++k) s += src[(size_t)k * (Mn * An)];
    atomicAdd(&PhiP[(size_t)m * An + a], s);
}

// ---------------------------------------------------------------------------
// K1-fallback (small ws): reads phi directly, owns sizeP.
// ---------------------------------------------------------------------------
__global__ __launch_bounds__(256) void k_phip_fb(const float* __restrict__ phi,
                                                 const float* __restrict__ E,
                                                 float* __restrict__ PhiP,
                                                 float* __restrict__ sizeP) {
    __shared__ float pv[64 * 16];
    __shared__ float szl[Mn];
    const int t = threadIdx.x;
    const int a4 = t & 31;
    const int g = t >> 5;
    const int vloc = t >> 2;
    const int mbase = 4 * (t & 3);

    if (t < Mn) szl[t] = 0.f;

    float4 acc0 = make_float4(0.f, 0.f, 0.f, 0.f);
    float4 acc1 = make_float4(0.f, 0.f, 0.f, 0.f);
    float4 szacc = make_float4(0.f, 0.f, 0.f, 0.f);

    for (int v0 = blockIdx.x * 64; v0 < Vn; v0 += gridDim.x * 64) {
        __syncthreads();
        const int v = v0 + vloc;
        float4 pj = make_float4(0.f, 0.f, 0.f, 0.f);
        if (v < Vn) {
            pj.x = sigm(phi[(size_t)(mbase + 0) * Vn + v]);
            pj.y = sigm(phi[(size_t)(mbase + 1) * Vn + v]);
            pj.z = sigm(phi[(size_t)(mbase + 2) * Vn + v]);
            pj.w = sigm(phi[(size_t)(mbase + 3) * Vn + v]);
        }
        *(float4*)&pv[4 * t] = pj;
        szacc.x += pj.x; szacc.y += pj.y; szacc.z += pj.z; szacc.w += pj.w;
        __syncthreads();
        const int vmax = min(64, Vn - v0);
#pragma unroll 8
        for (int vv = 0; vv < vmax; ++vv) {
            const float4 e = *(const float4*)&E[(size_t)(v0 + vv) * An + a4 * 4];
            const float2 pm = *(const float2*)&pv[vv * 16 + g * 2];
            acc0.x += pm.x * e.x; acc0.y += pm.x * e.y; acc0.z += pm.x * e.z; acc0.w += pm.x * e.w;
            acc1.x += pm.y * e.x; acc1.y += pm.y * e.y; acc1.z += pm.y * e.z; acc1.w += pm.y * e.w;
        }
    }
    {
        float* d0 = &PhiP[(size_t)(2 * g + 0) * An + a4 * 4];
        float* d1 = &PhiP[(size_t)(2 * g + 1) * An + a4 * 4];
        atomicAdd(d0 + 0, acc0.x); atomicAdd(d0 + 1, acc0.y);
        atomicAdd(d0 + 2, acc0.z); atomicAdd(d0 + 3, acc0.w);
        atomicAdd(d1 + 0, acc1.x); atomicAdd(d1 + 1, acc1.y);
        atomicAdd(d1 + 2, acc1.z); atomicAdd(d1 + 3, acc1.w);
    }
    atomicAdd(&szl[mbase + 0], szacc.x);
    atomicAdd(&szl[mbase + 1], szacc.y);
    atomicAdd(&szl[mbase + 2], szacc.z);
    atomicAdd(&szl[mbase + 3], szacc.w);
    __syncthreads();
    if (t < Mn) atomicAdd(&sizeP[t], szl[t]);
}

// ---------------------------------------------------------------------------
// K2: PhiQ[b,a] = sum_{i in seg b} E[qid[i],a];  sumpS[b,m] = sum_i pT[qid[i],m]
// grid (64 splits, B). block 256.
// ---------------------------------------------------------------------------
__global__ __launch_bounds__(256) void k_phiq(const int* __restrict__ qid,
                                              const int* __restrict__ offs,
                                              const float* __restrict__ E,
                                              const float* __restrict__ phi,
                                              const float* __restrict__ pT,
                                              int usepT,
                                              float* __restrict__ PhiQ,
                                              float* __restrict__ sumpS) {
    const int b = blockIdx.y;
    const int s0 = offs[b], s1 = offs[b + 1];
    const int len = s1 - s0;
    const int nsplit = (int)gridDim.x;
    const int chunk = (len + nsplit - 1) / nsplit;
    const int start = s0 + (int)blockIdx.x * chunk;
    const int end = min(start + chunk, s1);
    const int t = threadIdx.x;

    __shared__ float phl[8 * 128];
    __shared__ float sP[Mn];
    if (t < Mn) sP[t] = 0.f;

    {
        const int a4 = t & 31, sub = t >> 5;
        float4 acc = make_float4(0.f, 0.f, 0.f, 0.f);
        const float4* E4 = (const float4*)E;
        int i = start + sub;
        for (; i + 56 < end; i += 64) {
            int q[8];
#pragma unroll
            for (int k = 0; k < 8; ++k) q[k] = qid[i + 8 * k];
            float4 e[8];
#pragma unroll
            for (int k = 0; k < 8; ++k) e[k] = E4[(size_t)q[k] * 32 + a4];
#pragma unroll
            for (int k = 0; k < 8; ++k) {
                acc.x += e[k].x; acc.y += e[k].y;
                acc.z += e[k].z; acc.w += e[k].w;
            }
        }
        for (; i < end; i += 8) {
            const float4 e = E4[(size_t)qid[i] * 32 + a4];
            acc.x += e.x; acc.y += e.y; acc.z += e.z; acc.w += e.w;
        }
        *(float4*)&phl[sub * 128 + a4 * 4] = acc;
    }
    __syncthreads();
    if (t < 128) {
        float s = 0.f;
#pragma unroll
        for (int k = 0; k < 8; ++k) s += phl[k * 128 + t];
        atomicAdd(&PhiQ[(size_t)b * An + t], s);
    }

    float4 acc = make_float4(0.f, 0.f, 0.f, 0.f);
    const int m4 = t & 3, io = t >> 2;
    if (usepT) {
        const float4* pT4 = (const float4*)pT;
        int i = start + io;
        for (; i + 192 < end; i += 256) {
            const int q0 = qid[i], q1 = qid[i + 64], q2 = qid[i + 128], q3 = qid[i + 192];
            const float4 p0 = pT4[(size_t)q0 * 4 + m4];
            const float4 p1 = pT4[(size_t)q1 * 4 + m4];
            const float4 p2 = pT4[(size_t)q2 * 4 + m4];
            const float4 p3 = pT4[(size_t)q3 * 4 + m4];
            acc.x += p0.x + p1.x + p2.x + p3.x;
            acc.y += p0.y + p1.y + p2.y + p3.y;
            acc.z += p0.z + p1.z + p2.z + p3.z;
            acc.w += p0.w + p1.w + p2.w + p3.w;
        }
        for (; i < end; i += 64) {
            const float4 p = pT4[(size_t)qid[i] * 4 + m4];
            acc.x += p.x; acc.y += p.y; acc.z += p.z; acc.w += p.w;
        }
    } else {
        for (int i = start + io; i < end; i += 64) {
            const int q = qid[i];
            acc.x += sigm(phi[(size_t)(m4 * 4 + 0) * Vn + q]);
            acc.y += sigm(phi[(size_t)(m4 * 4 + 1) * Vn + q]);
            acc.z += sigm(phi[(size_t)(m4 * 4 + 2) * Vn + q]);
            acc.w += sigm(phi[(size_t)(m4 * 4 + 3) * Vn + q]);
        }
    }
#pragma unroll
    for (int off = 32; off >= 4; off >>= 1) {
        acc.x += __shfl_xor(acc.x, off);
        acc.y += __shfl_xor(acc.y, off);
        acc.z += __shfl_xor(acc.z, off);
        acc.w += __shfl_xor(acc.w, off);
    }
    if ((t & 63) < 4) {
        atomicAdd(&sP[m4 * 4 + 0], acc.x);
        atomicAdd(&sP[m4 * 4 + 1], acc.y);
        atomicAdd(&sP[m4 * 4 + 2], acc.z);
        atomicAdd(&sP[m4 * 4 + 3], acc.w);
    }
    __syncthreads();
    if (t < Mn) atomicAdd(&sumpS[(size_t)b * Mn + t], sP[t]);
}

// ---------------------------------------------------------------------------
// K2b (NEW): b-independent precompute. grid (Mn) x 192.
// BP[m][a] = dot(W_B[a,:], PhiP[m,:]);  Vp[m][hd] = dot(W_val[hd,:], PhiP[m,:])+b_val
// Was recomputed 64x inside k_small as its dominant serial chain (k_small
// measured 43us at 1.1% VALU / 1.1% occupancy — pure exposed latency).
// ---------------------------------------------------------------------------
__global__ __launch_bounds__(192) void k_bp(const float* __restrict__ PhiP,
                                            const float* __restrict__ W_B,
                                            const float* __restrict__ W_val,
                                            const float* __restrict__ b_val,
                                            float* __restrict__ BP,
                                            float* __restrict__ Vp) {
    const int m = blockIdx.x;
    const int t = threadIdx.x;
    const float4* pp = (const float4*)(PhiP + (size_t)m * An);
    if (t < 128) {
        const float4* wb = (const float4*)(W_B + (size_t)t * An);
        float s = 0.f;
#pragma unroll
        for (int q = 0; q < An / 4; ++q) {
            const float4 w = wb[q], p = pp[q];
            s += w.x * p.x + w.y * p.y + w.z * p.z + w.w * p.w;
        }
        BP[(size_t)m * An + t] = s;
    } else if (t < 128 + HDn) {
        const int hd = t - 128;
        const float4* wv = (const float4*)(W_val + (size_t)hd * An);
        float s = 0.f;
#pragma unroll
        for (int q = 0; q < An / 4; ++q) {
            const float4 w = wv[q], p = pp[q];
            s += w.x * p.x + w.y * p.y + w.z * p.z + w.w * p.w;
        }
        Vp[(size_t)m * HDn + hd] = s + b_val[hd];
    }
}

// ---------------------------------------------------------------------------
// K3 (slim): per-b block (128 thr). Uses precomputed BP/Vp. Phases:
// AQ (32 f4 FMA/thr) -> scores (8-lane split dot + 3 shuffles) -> softmax
// -> Z (16 FMA) -> C (4x32 FMA). Longest chain ~20x shorter than old k_small.
// ---------------------------------------------------------------------------
__global__ __launch_bounds__(128) void k_small(const float* __restrict__ BP,
                                               const float* __restrict__ Vp,
                                               const float* __restrict__ sizeP,
                                               const float* __restrict__ PhiQ,
                                               const float* __restrict__ sumpS,
                                               const int* __restrict__ offs,
                                               const float* __restrict__ W_A,
                                               const float* __restrict__ W_out,
                                               const float* __restrict__ size_w,
                                               float* __restrict__ Cws) {
    const int b = blockIdx.x;
    const int i = threadIdx.x;
    __shared__ float AQs[An];
    __shared__ float sc[Mn];
    __shared__ float attn[Mn];
    __shared__ float Zs[HDn];

    {   // AQ[i] = dot(W_A[i,:], PhiQ[b,:])
        const float4* wa = (const float4*)(W_A + (size_t)i * An);
        const float4* pq = (const float4*)(PhiQ + (size_t)b * An);
        float aq = 0.f;
#pragma unroll
        for (int q = 0; q < An / 4; ++q) {
            const float4 w = wa[q], p = pq[q];
            aq += w.x * p.x + w.y * p.y + w.z * p.z + w.w * p.w;
        }
        AQs[i] = aq;
    }
    __syncthreads();

    const float szQ = (float)(offs[b + 1] - offs[b]);
    {   // scores: thread = (m = i>>3, l8 = i&7); each lane dots 16 of 128
        const int m = i >> 3, l8 = i & 7;
        const float4* bp = (const float4*)(BP + (size_t)m * An + l8 * 16);
        const float4* aq = (const float4*)(AQs + l8 * 16);
        float s = 0.f;
#pragma unroll
        for (int q = 0; q < 4; ++q) {
            const float4 w = bp[q], p = aq[q];
            s += w.x * p.x + w.y * p.y + w.z * p.z + w.w * p.w;
        }
        s += __shfl_xor(s, 1);
        s += __shfl_xor(s, 2);
        s += __shfl_xor(s, 4);
        if (l8 == 0) {
            const float delta = szQ + sizeP[m] - 2.f * sumpS[(size_t)b * Mn + m];
            sc[m] = -GAMMA * delta + BETA * s + size_w[0] * szQ + size_w[1] * sizeP[m];
        }
    }
    __syncthreads();
    if (i < Mn) {
        float mx = sc[0];
#pragma unroll
        for (int m = 1; m < Mn; ++m) mx = fmaxf(mx, sc[m]);
        float sum = 0.f;
#pragma unroll
        for (int m = 0; m < Mn; ++m) sum += __expf(sc[m] - mx);
        attn[i] = __expf(sc[i] - mx) / sum;
    }
    __syncthreads();
    if (i < HDn) {
        float z = 0.f;
#pragma unroll
        for (int m = 0; m < Mn; ++m) z += attn[m] * Vp[(size_t)m * HDn + i];
        Zs[i] = z;
    }
    __syncthreads();
    {
        const float* wo = W_out + (size_t)i * Dn;
#pragma unroll
        for (int h = 0; h < Hn; ++h) {
            float c = 0.f;
#pragma unroll
            for (int j = 0; j < HDn; ++j) c += Zs[j] * wo[h * HDn + j];
            Cws[((size_t)b * Hn + h) * Dn + i] = c;
        }
    }
}

// ---------------------------------------------------------------------------
// K3-fallback (small ws): original monolithic per-b kernel.
// ---------------------------------------------------------------------------
__global__ __launch_bounds__(128) void k_small_fb(const float* __restrict__ PhiP,
                                                  const float* __restrict__ sizeP,
                                                  const float* __restrict__ PhiQ,
                                                  const float* __restrict__ sumpS,
                                                  const int* __restrict__ offs,
                                                  const float* __restrict__ W_A,
                                                  const float* __restrict__ W_B,
                                                  const float* __restrict__ W_val,
                                                  const float* __restrict__ b_val,
                                                  const float* __restrict__ W_out,
                                                  const float* __restrict__ size_w,
                                                  float* __restrict__ Cws) {
    const int b = blockIdx.x;
    const int i = threadIdx.x;
    __shared__ float BP[Mn * An];
    __shared__ float Vp[Mn * HDn];
    __shared__ float AQs[An];
    __shared__ float sc[Mn];
    __shared__ float attn[Mn];
    __shared__ float Zs[HDn];

    {
        const float4* wa = (const float4*)(W_A + (size_t)i * An);
        const float4* pq = (const float4*)(PhiQ + (size_t)b * An);
        float aq = 0.f;
        for (int q = 0; q < An / 4; ++q) {
            const float4 w = wa[q], p = pq[q];
            aq += w.x * p.x + w.y * p.y + w.z * p.z + w.w * p.w;
        }
        AQs[i] = aq;
    }
    {
        const float4* wb = (const float4*)(W_B + (size_t)i * An);
        for (int m = 0; m < Mn; ++m) {
            const float4* pp = (const float4*)(PhiP + (size_t)m * An);
            float s = 0.f;
            for (int q = 0; q < An / 4; ++q) {
                const float4 w = wb[q], p = pp[q];
                s += w.x * p.x + w.y * p.y + w.z * p.z + w.w * p.w;
            }
            BP[m * An + i] = s;
        }
    }
    if (i < HDn) {
        const float4* wv = (const float4*)(W_val + (size_t)i * An);
        for (int m = 0; m < Mn; ++m) {
            const float4* pp = (const float4*)(PhiP + (size_t)m * An);
            float s = 0.f;
            for (int q = 0; q < An / 4; ++q) {
                const float4 w = wv[q], p = pp[q];
                s += w.x * p.x + w.y * p.y + w.z * p.z + w.w * p.w;
            }
            Vp[m * HDn + i] = s + b_val[i];
        }
    }
    __syncthreads();

    const float szQ = (float)(offs[b + 1] - offs[b]);
    if (i < Mn) {
        float d = 0.f;
        for (int a = 0; a < An; ++a) d += AQs[a] * BP[i * An + a];
        const float delta = szQ + sizeP[i] - 2.f * sumpS[(size_t)b * Mn + i];
        sc[i] = -GAMMA * delta + BETA * d + size_w[0] * szQ + size_w[1] * sizeP[i];
    }
    __syncthreads();
    if (i < Mn) {
        float mx = sc[0];
        for (int m = 1; m < Mn; ++m) mx = fmaxf(mx, sc[m]);
        float sum = 0.f;
        for (int m = 0; m < Mn; ++m) sum += __expf(sc[m] - mx);
        attn[i] = __expf(sc[i] - mx) / sum;
    }
    __syncthreads();
    if (i < HDn) {
        float z = 0.f;
        for (int m = 0; m < Mn; ++m) z += attn[m] * Vp[m * HDn + i];
        Zs[i] = z;
    }
    __syncthreads();
    {
        const float* wo = W_out + (size_t)i * Dn;
#pragma unroll
        for (int h = 0; h < Hn; ++h) {
            float c = 0.f;
#pragma unroll
            for (int j = 0; j < HDn; ++j) c += Zs[j] * wo[h * HDn + j];
            Cws[((size_t)b * Hn + h) * Dn + i] = c;
        }
    }
}

// ---------------------------------------------------------------------------
// K4: out[b,l,:] = b_out + sum_h softmax_h(ts[b,l,:].W_gate[h]+b_gate) * C[b,h,:]
// FROZEN at v5 (batch-8): 4 structurally different inner loops all measure
// 42-47us at ~2.3TB/s HBM — memory-system bound, not core-loop bound.
// ---------------------------------------------------------------------------
__global__ __launch_bounds__(256) void k_out(const float* __restrict__ ts,
                                             const float* __restrict__ W_gate,
                                             const float* __restrict__ b_gate,
                                             const float* __restrict__ b_out,
                                             const float* __restrict__ Cws,
                                             float* __restrict__ out) {
    constexpr int CHUNK = 64;
    constexpr int NIT = CHUNK / 8;   // 8 iterations, 8 tokens in flight/block
    const int b = blockIdx.y;
    const int t = threadIdx.x;
    __shared__ float4 WgS[Hn * 32];
    __shared__ float4 CS[Hn * 32];
    __shared__ float4 boS[32];
    __shared__ float bgS[Hn];
    if (t < 128) WgS[t] = ((const float4*)W_gate)[t];
    else CS[t - 128] = ((const float4*)(Cws + (size_t)b * Hn * Dn))[t - 128];
    if (t < 32) boS[t] = ((const float4*)b_out)[t];
    if (t >= 64 && t < 64 + Hn) bgS[t - 64] = b_gate[t - 64];
    __syncthreads();

    const int sl = t & 31;
    const int tg = t >> 5;
    const size_t rowbase = (size_t)b * Ln + (size_t)blockIdx.x * CHUNK;
    const float4* x4 = (const float4*)ts + rowbase * 32;
    nfloat4* o4 = (nfloat4*)out + rowbase * 32;

    const float4 w0 = WgS[0 * 32 + sl], w1 = WgS[1 * 32 + sl];
    const float4 w2 = WgS[2 * 32 + sl], w3 = WgS[3 * 32 + sl];
    const float4 c0 = CS[0 * 32 + sl], c1 = CS[1 * 32 + sl];
    const float4 c2 = CS[2 * 32 + sl], c3 = CS[3 * 32 + sl];
    const float4 bo = boS[sl];
    const float bg0 = bgS[0], bg1 = bgS[1], bg2 = bgS[2], bg3 = bgS[3];

    // batch-issue all 8 loads (independent; 8 outstanding per wave)
    float4 x[NIT];
#pragma unroll
    for (int k = 0; k < NIT; ++k)
        x[k] = x4[(size_t)(k * 8 + tg) * 32 + sl];

#pragma unroll
    for (int it = 0; it < NIT; ++it) {
        const float4 xi = x[it];
        float a0 = xi.x * w0.x + xi.y * w0.y + xi.z * w0.z + xi.w * w0.w;
        float a1 = xi.x * w1.x + xi.y * w1.y + xi.z * w1.z + xi.w * w1.w;
        float a2 = xi.x * w2.x + xi.y * w2.y + xi.z * w2.z + xi.w * w2.w;
        float a3 = xi.x * w3.x + xi.y * w3.y + xi.z * w3.z + xi.w * w3.w;
#pragma unroll
        for (int off = 16; off > 0; off >>= 1) {
            a0 += __shfl_xor(a0, off);
            a1 += __shfl_xor(a1, off);
            a2 += __shfl_xor(a2, off);
            a3 += __shfl_xor(a3, off);
        }
        a0 += bg0; a1 += bg1; a2 += bg2; a3 += bg3;
        const float mx = fmaxf(fmaxf(a0, a1), fmaxf(a2, a3));
        const float e0 = __expf(a0 - mx), e1 = __expf(a1 - mx);
        const float e2 = __expf(a2 - mx), e3 = __expf(a3 - mx);
        const float inv = 1.f / (e0 + e1 + e2 + e3);
        const float g0 = e0 * inv, g1 = e1 * inv, g2 = e2 * inv, g3 = e3 * inv;
        nfloat4 o;
        o.x = bo.x + g0 * c0.x + g1 * c1.x + g2 * c2.x + g3 * c3.x;
        o.y = bo.y + g0 * c0.y + g1 * c1.y + g2 * c2.y + g3 * c3.y;
        o.z = bo.z + g0 * c0.z + g1 * c1.z + g2 * c2.z + g3 * c3.z;
        o.w = bo.w + g0 * c0.w + g1 * c1.w + g2 * c2.w + g3 * c3.w;
        __builtin_nontemporal_store(o, &o4[(size_t)(it * 8 + tg) * 32 + sl]);
    }
}

extern "C" void kernel_launch(void* const* d_in, const int* in_sizes, int n_in,
                              void* d_out, int out_size, void* d_ws, size_t ws_size,
                              hipStream_t stream) {
    const float* ts     = (const float*)d_in[0];
    const int*   qid    = (const int*)d_in[1];
    const int*   offs   = (const int*)d_in[2];
    const float* E      = (const float*)d_in[3];
    const float* phi    = (const float*)d_in[4];
    const float* W_A    = (const float*)d_in[5];
    const float* W_B    = (const float*)d_in[6];
    const float* W_val  = (const float*)d_in[7];
    const float* b_val  = (const float*)d_in[8];
    const float* W_gate = (const float*)d_in[9];
    const float* b_gate = (const float*)d_in[10];
    const float* W_out  = (const float*)d_in[11];
    const float* b_out  = (const float*)d_in[12];
    const float* size_w = (const float*)d_in[13];
    float* out = (float*)d_out;
    float* ws  = (float*)d_ws;

    float* PhiP  = ws + OFF_PHIP;
    float* sizeP = ws + OFF_SIZEP;
    float* PhiQ  = ws + OFF_PHIQ;
    float* sumpS = ws + OFF_SUMPS;
    float* Cws   = ws + OFF_C;
    float* pT    = ws + OFF_PT;
    float* part  = ws + OFF_PART;
    float* BPws  = ws + OFF_BP;
    float* Vpws  = ws + OFF_VP;
    const int usepT   = (ws_size >= WS_FLOATS_PT * sizeof(float)) ? 1 : 0;
    const int usePart = (ws_size >= WS_FLOATS_PART * sizeof(float)) ? 1 : 0;
    const int useBP   = (ws_size >= WS_FLOATS_BP * sizeof(float)) ? 1 : 0;

    hipMemsetAsync(ws, 0, OFF_C * sizeof(float), stream);  // zero accumulators
    if (usepT) {
        k_pt<<<dim3((Vn + 255) / 256), dim3(256), 0, stream>>>(phi, pT, sizeP);
        k_phip<<<dim3(PHIP_BLOCKS), dim3(256), 0, stream>>>(E, pT, PhiP, part,
                                                            usePart ? 0 : 1);
        if (usePart)
            k_red<<<dim3(Mn, 64), dim3(128), 0, stream>>>(part, PhiP);
    } else {
        k_phip_fb<<<dim3(512), dim3(256), 0, stream>>>(phi, E, PhiP, sizeP);
    }
    k_phiq<<<dim3(64, Bn), dim3(256), 0, stream>>>(qid, offs, E, phi, pT, usepT, PhiQ, sumpS);
    if (useBP) {
        k_bp<<<dim3(Mn), dim3(192), 0, stream>>>(PhiP, W_B, W_val, b_val, BPws, Vpws);
        k_small<<<dim3(Bn), dim3(128), 0, stream>>>(BPws, Vpws, sizeP, PhiQ, sumpS, offs,
                                                    W_A, W_out, size_w, Cws);
    } else {
        k_small_fb<<<dim3(Bn), dim3(128), 0, stream>>>(PhiP, sizeP, PhiQ, sumpS, offs,
                                                       W_A, W_B, W_val, b_val, W_out,
                                                       size_w, Cws);
    }
    k_out<<<dim3(Ln / 64, Bn), dim3(256), 0, stream>>>(ts, W_gate, b_gate, b_out, Cws, out);
}